// Round 3
// baseline (309.202 us; speedup 1.0000x reference)
//
#include <hip/hip_runtime.h>
#include <hip/hip_bf16.h>
#include <stdint.h>

// out[M,N] = x[M,K] @ weight[N,K]^T ; M=8192, N=4096, K=4096, fp32 in/out.
// Pass 1: fp32 -> bf16 convert (memory-bound) into d_ws.
// Pass 2: 256x256 8-wave 8-phase bf16 MFMA GEMM, m201 skeleton:
//   T1 XCD swizzle, T2 st-swizzled LDS, T3/T4 8-phase counted vmcnt(4),
//   T5 setprio. Round 3: 32x32x16 MFMA (2495 vs 2075 TF ceiling), compiler
//   counted lgkmcnt (dropped blanket lgkmcnt(0)).

typedef __bf16 bf16x8 __attribute__((ext_vector_type(8)));
typedef float f32x4 __attribute__((ext_vector_type(4)));
typedef float f32x16 __attribute__((ext_vector_type(16)));

__device__ __forceinline__ unsigned short f2bf(float f) {
  unsigned u = __builtin_bit_cast(unsigned, f);
  u += 0x7FFFu + ((u >> 16) & 1u);  // RNE; Gaussian inputs, no NaN
  return (unsigned short)(u >> 16);
}

__global__ void cvt_f32_to_bf16(const float* __restrict__ src,
                                unsigned short* __restrict__ dst, long n4) {
  long i = (long)blockIdx.x * blockDim.x + threadIdx.x;
  const long stride = (long)gridDim.x * blockDim.x;
  for (; i < n4; i += stride) {
    float4 v = reinterpret_cast<const float4*>(src)[i];
    ushort4 o;
    o.x = f2bf(v.x); o.y = f2bf(v.y); o.z = f2bf(v.z); o.w = f2bf(v.w);
    reinterpret_cast<ushort4*>(dst)[i] = o;
  }
}

__device__ __forceinline__ void gload_lds16(const void* g, void* lds) {
  // async global->LDS, 16B/lane; LDS dest = wave-uniform base + lane*16
  __builtin_amdgcn_global_load_lds(
      (__attribute__((address_space(1))) void*)(g),
      (__attribute__((address_space(3))) void*)(lds), 16, 0, 0);
}

#define BARRIER()                                    \
  do {                                               \
    asm volatile("" ::: "memory");                   \
    __builtin_amdgcn_s_barrier();                    \
    asm volatile("" ::: "memory");                   \
  } while (0)
#define WAIT_VM4() asm volatile("s_waitcnt vmcnt(4)" ::: "memory")
#define WAIT_VM0() asm volatile("s_waitcnt vmcnt(0)" ::: "memory")

// ---- fragment reads (all indices compile-time after unroll; rule #20) ----
// A-frag (32x32x16): lane holds row = l&31, k = (l>>5)*8 + i. One b128/frag.
// Byte addr swizzle: row&7 == l&7 for every 32-row block -> xc const/lane.
#define READ_A(AB, P)                                                        \
  _Pragma("unroll") for (int mi = 0; mi < 2; ++mi) {                         \
    const int row_ = ((P)*2 + mi) * 32 + l31;                                \
    _Pragma("unroll") for (int ks = 0; ks < 4; ++ks)                         \
        fa[(P)*2 + mi][ks] =                                                 \
            *(const bf16x8*)((AB) + row_ * 128 + ((kq + ks * 32) ^ xc));     \
  }
#define READ_B(BB, NI)                                                       \
  {                                                                          \
    const int row_ = brow0 + (NI)*32 + l31;                                  \
    _Pragma("unroll") for (int ks = 0; ks < 4; ++ks)                         \
        fb[NI][ks] =                                                         \
            *(const bf16x8*)((BB) + row_ * 128 + ((kq + ks * 32) ^ xc));     \
  }
// 8 MFMA: mi-pair P x col-block NI, 4 k-slices; 2 indep acc chains depth 4.
#define MQ(P, NI)                                                            \
  _Pragma("unroll") for (int ks = 0; ks < 4; ++ks)                           \
  _Pragma("unroll") for (int mi = 0; mi < 2; ++mi)                           \
      acc[(P)*2 + mi][NI] = __builtin_amdgcn_mfma_f32_32x32x16_bf16(         \
          fa[(P)*2 + mi][ks], fb[NI][ks], acc[(P)*2 + mi][NI], 0, 0, 0);

// phase: {reads || stage} -> barrier -> prio1 8xMFMA prio0 -> [vm] -> barrier
// (no blanket lgkmcnt(0): loads are compiler-visible; hipcc emits counted
//  lgkmcnt per consumer, letting early MFMAs overlap late ds_reads)
#define PH(READS, STAGES, MQCALL, WAITS)  \
  do {                                    \
    READS STAGES BARRIER();               \
    __builtin_amdgcn_s_setprio(1);        \
    MQCALL                                \
    __builtin_amdgcn_s_setprio(0);        \
    WAITS BARRIER();                      \
  } while (0)

__global__ __launch_bounds__(512, 2) void gemm256(
    const unsigned short* __restrict__ A, const unsigned short* __restrict__ B,
    float* __restrict__ C, int M, int N, int K) {
  // LDS: A halves at (buf*2+h)*16384 ; B at 65536 + (buf*2+h)*16384
  __shared__ __attribute__((aligned(1024))) char lds[131072];
  const int A00 = 0, A01 = 16384, A10 = 32768, A11 = 49152;
  const int B00 = 65536, B01 = 81920, B10 = 98304, B11 = 114688;

  const int t = threadIdx.x;
  const int l = t & 63;
  const int w = t >> 6;        // wave 0..7
  const int wm = w >> 2;       // 0..1 : 128-row half of the 256-row tile
  const int wn = w & 3;        // 0..3 : 64-col strip of the 256-col tile
  const int l31 = l & 31;
  const int kq = (l >> 5) * 16;           // k-group byte offset (8 bf16)
  const int xc = (l & 7) << 4;            // swizzle const (row&7 == l&7)
  const int brow0 = (wn & 1) * 64;        // row offset inside B half
  const int srow = l >> 3;                // staging row within 8-row chunk
  const int sslot = ((l & 7) ^ ((l >> 3) & 7)) * 8;  // pre-swizzled src slot

  // T1: bijective XCD swizzle (nwg % 8 == 0 here)
  const int nwg = gridDim.x;
  int swz = blockIdx.x;
  if ((nwg & 7) == 0) swz = (swz & 7) * (nwg >> 3) + (swz >> 3);
  const int ntx = N >> 8;
  const int bx = swz % ntx;
  const int by = swz / ntx;
  const int mBase = by * 256, nBase = bx * 256;

  // read bases: wave's A half per buffer, B half per buffer
  const char* Ard0 = lds + wm * 16384;
  const char* Ard1 = lds + 32768 + wm * 16384;
  const char* Brd0 = lds + 65536 + (wn >> 1) * 16384;
  const char* Brd1 = lds + 98304 + (wn >> 1) * 16384;

  bf16x8 fa[4][2 * 2], fb[2][4];  // fa[frag-row][ks], fb[col-block][ks]
  f32x16 acc[4][2] = {};

  auto STAGE = [&](const unsigned short* __restrict__ G, int row0, int k0,
                   int ldsOff) {
    const unsigned short* s =
        G + (size_t)(row0 + w * 8 + srow) * K + k0 + sslot;
    char* d = lds + ldsOff + w * 1024;
    gload_lds16(s, d);                          // rows 0-63 of the half
    gload_lds16(s + (size_t)64 * K, d + 8192);  // rows 64-127
  };

  // ---- prologue: tile0 (4 halves) + B10,A10 of tile1; drain tile0 ----
  STAGE(A, mBase, 0, A00);
  STAGE(A, mBase + 128, 0, A01);
  STAGE(B, nBase, 0, B00);
  STAGE(B, nBase + 128, 0, B01);
  STAGE(B, nBase, 64, B10);
  STAGE(A, mBase, 64, A10);
  WAIT_VM4();
  BARRIER();

  // ---- main loop: iteration i computes tiles 2i (buf0), 2i+1 (buf1) ----
  const int itermain = K / 128 - 1;
  for (int i = 0; i < itermain; ++i) {
    const int kA = (2 * i + 1) * 64;  // tile 2i+1
    const int kB = kA + 64;           // tile 2i+2
    const int kC = kB + 64;           // tile 2i+3
    PH(READ_A(Ard0, 0) READ_B(Brd0, 0), STAGE(A, mBase + 128, kA, A11);, MQ(0, 0), );
    PH(READ_B(Brd0, 1),                 STAGE(B, nBase + 128, kA, B11);, MQ(0, 1), );
    PH(READ_A(Ard0, 1),                 STAGE(B, nBase,       kB, B00);, MQ(1, 0), );
    PH(,                                STAGE(A, mBase,       kB, A00);, MQ(1, 1), WAIT_VM4(););
    PH(READ_A(Ard1, 0) READ_B(Brd1, 0), STAGE(A, mBase + 128, kB, A01);, MQ(0, 0), );
    PH(READ_B(Brd1, 1),                 STAGE(B, nBase + 128, kB, B01);, MQ(0, 1), );
    PH(READ_A(Ard1, 1),                 STAGE(B, nBase,       kC, B10);, MQ(1, 0), );
    PH(,                                STAGE(A, mBase,       kC, A10);, MQ(1, 1), WAIT_VM4(););
  }

  // ---- tail: tiles nt-2 (buf0), nt-1 (buf1) ----
  {
    const int kT = K - 64;  // last tile
    PH(READ_A(Ard0, 0) READ_B(Brd0, 0), STAGE(A, mBase + 128, kT, A11);, MQ(0, 0), );
    PH(READ_B(Brd0, 1),                 STAGE(B, nBase + 128, kT, B11);, MQ(0, 1), );
    PH(READ_A(Ard0, 1),                 ,                                MQ(1, 0), );
    PH(,                                ,                                MQ(1, 1), WAIT_VM0(););
    PH(READ_A(Ard1, 0) READ_B(Brd1, 0), ,                                MQ(0, 0), );
    PH(READ_B(Brd1, 1),                 ,                                MQ(0, 1), );
    PH(READ_A(Ard1, 1),                 ,                                MQ(1, 0), );
    PH(,                                ,                                MQ(1, 1), );
  }

  // ---- epilogue: 32x32 C/D layout (m74/m101-verified):
  //      col = lane&31, row = (reg&3) + 8*(reg>>2) + 4*(lane>>5) ----
  const int cl = l & 31, ch = l >> 5;
  float* Cw = C + (size_t)(mBase + wm * 128 + 4 * ch) * N + nBase + wn * 64 + cl;
#pragma unroll
  for (int mi = 0; mi < 4; ++mi)
#pragma unroll
    for (int ni = 0; ni < 2; ++ni)
#pragma unroll
      for (int r = 0; r < 16; ++r)
        Cw[(size_t)(mi * 32 + (r & 3) + 8 * (r >> 2)) * N + ni * 32] =
            acc[mi][ni][r];
}

// ---- fallback (round-1 verified fused path; used only if ws too small) ----
typedef unsigned short ushort8f __attribute__((ext_vector_type(8)));
__global__ __launch_bounds__(256) void gemm_fb(
    const float* __restrict__ Af, const float* __restrict__ Wf,
    float* __restrict__ C, int M, int N, int K) {
  __shared__ __attribute__((aligned(16))) unsigned short Ash[128 * 64];
  __shared__ __attribute__((aligned(16))) unsigned short Bsh[128 * 64];
  const int t = threadIdx.x, l = t & 63, w = t >> 6;
  const int mBase = blockIdx.y * 128, nBase = blockIdx.x * 128;
  const int wm = w >> 1, wn = w & 1;
  const int lr = l & 15, lk = (l >> 4) * 8;
  f32x4 acc[4][4] = {};
  const int frow = t >> 1, fkh = (t & 1) * 32;
  for (int k0 = 0; k0 < K; k0 += 64) {
    const float* ga = Af + (size_t)(mBase + frow) * K + k0 + fkh;
    const float* gb = Wf + (size_t)(nBase + frow) * K + k0 + fkh;
#pragma unroll
    for (int j = 0; j < 4; ++j) {
      float4 a0 = reinterpret_cast<const float4*>(ga)[2 * j];
      float4 a1 = reinterpret_cast<const float4*>(ga)[2 * j + 1];
      float4 b0 = reinterpret_cast<const float4*>(gb)[2 * j];
      float4 b1 = reinterpret_cast<const float4*>(gb)[2 * j + 1];
      ushort8f oa = {f2bf(a0.x), f2bf(a0.y), f2bf(a0.z), f2bf(a0.w),
                     f2bf(a1.x), f2bf(a1.y), f2bf(a1.z), f2bf(a1.w)};
      ushort8f ob = {f2bf(b0.x), f2bf(b0.y), f2bf(b0.z), f2bf(b0.w),
                     f2bf(b1.x), f2bf(b1.y), f2bf(b1.z), f2bf(b1.w)};
      *reinterpret_cast<ushort8f*>(&Ash[frow * 64 + fkh + j * 8]) = oa;
      *reinterpret_cast<ushort8f*>(&Bsh[frow * 64 + fkh + j * 8]) = ob;
    }
    __syncthreads();
#pragma unroll
    for (int kk = 0; kk < 2; ++kk) {
      bf16x8 a[4], b[4];
#pragma unroll
      for (int mi = 0; mi < 4; ++mi)
        a[mi] = *reinterpret_cast<const bf16x8*>(
            &Ash[(wm * 64 + mi * 16 + lr) * 64 + kk * 32 + lk]);
#pragma unroll
      for (int ni = 0; ni < 4; ++ni)
        b[ni] = *reinterpret_cast<const bf16x8*>(
            &Bsh[(wn * 64 + ni * 16 + lr) * 64 + kk * 32 + lk]);
#pragma unroll
      for (int mi = 0; mi < 4; ++mi)
#pragma unroll
        for (int ni = 0; ni < 4; ++ni)
          acc[mi][ni] = __builtin_amdgcn_mfma_f32_16x16x32_bf16(
              a[mi], b[ni], acc[mi][ni], 0, 0, 0);
    }
    __syncthreads();
  }
  const int crow0 = mBase + wm * 64 + (l >> 4) * 4;
  const int ccol0 = nBase + wn * 64 + lr;
#pragma unroll
  for (int mi = 0; mi < 4; ++mi)
#pragma unroll
    for (int ni = 0; ni < 4; ++ni)
#pragma unroll
      for (int r = 0; r < 4; ++r)
        C[(size_t)(crow0 + mi * 16 + r) * N + ccol0 + ni * 16] =
            acc[mi][ni][r];
}

extern "C" void kernel_launch(void* const* d_in, const int* in_sizes, int n_in,
                              void* d_out, int out_size, void* d_ws, size_t ws_size,
                              hipStream_t stream) {
  (void)n_in; (void)out_size;
  const float* x = (const float*)d_in[0];
  const float* wgt = (const float*)d_in[1];
  float* out = (float*)d_out;

  const long x_elems = in_sizes[0];  // M*K
  const long w_elems = in_sizes[1];  // N*K
  const int K = 4096;
  const int M = (int)(x_elems / K);  // 8192
  const int N = (int)(w_elems / K);  // 4096

  const size_t need = (size_t)(x_elems + w_elems) * sizeof(unsigned short);
  const bool ok256 =
      (M % 256 == 0) && (N % 256 == 0) && (K % 128 == 0) && (K >= 256) &&
      ws_size >= need;
  if (ok256) {
    unsigned short* Abf = (unsigned short*)d_ws;
    unsigned short* Wbf = Abf + x_elems;
    cvt_f32_to_bf16<<<2048, 256, 0, stream>>>(x, Abf, x_elems / 4);
    cvt_f32_to_bf16<<<2048, 256, 0, stream>>>(wgt, Wbf, w_elems / 4);
    gemm256<<<dim3((M / 256) * (N / 256)), 512, 0, stream>>>(Abf, Wbf, out, M,
                                                             N, K);
  } else {
    dim3 grid(N / 128, M / 128);
    gemm_fb<<<grid, 256, 0, stream>>>(x, wgt, out, M, N, K);
  }
}

// Round 4
// 275.324 us; speedup vs baseline: 1.1230x; 1.1230x over previous
//
#include <hip/hip_runtime.h>
#include <hip/hip_bf16.h>
#include <stdint.h>

// out[M,N] = x[M,K] @ weight[N,K]^T ; M=8192, N=4096, K=4096, fp32 in/out.
// Pass 1: fp32 -> bf16 convert (memory-bound) into d_ws.
// Pass 2: 256x256 8-wave 8-phase bf16 MFMA GEMM (m201 skeleton, 16x16x32
//   MFMA as verified in round 2: 242us / 0 bank conflicts).
// Round 4 change: hoist each phase's ds_reads one phase EARLIER (into the
//   previous phase's MFMA region) so the LDS pipe drains while the matrix
//   pipe is busy. Phases 1/5 keep in-phase reads (their buffer is synced
//   only by the immediately preceding barrier).

typedef __bf16 bf16x8 __attribute__((ext_vector_type(8)));
typedef float f32x4 __attribute__((ext_vector_type(4)));

__device__ __forceinline__ unsigned short f2bf(float f) {
  unsigned u = __builtin_bit_cast(unsigned, f);
  u += 0x7FFFu + ((u >> 16) & 1u);  // RNE; Gaussian inputs, no NaN
  return (unsigned short)(u >> 16);
}

__global__ void cvt_f32_to_bf16(const float* __restrict__ src,
                                unsigned short* __restrict__ dst, long n4) {
  long i = (long)blockIdx.x * blockDim.x + threadIdx.x;
  const long stride = (long)gridDim.x * blockDim.x;
  for (; i < n4; i += stride) {
    float4 v = reinterpret_cast<const float4*>(src)[i];
    ushort4 o;
    o.x = f2bf(v.x); o.y = f2bf(v.y); o.z = f2bf(v.z); o.w = f2bf(v.w);
    reinterpret_cast<ushort4*>(dst)[i] = o;
  }
}

__device__ __forceinline__ void gload_lds16(const void* g, void* lds) {
  // async global->LDS, 16B/lane; LDS dest = wave-uniform base + lane*16
  __builtin_amdgcn_global_load_lds(
      (__attribute__((address_space(1))) void*)(g),
      (__attribute__((address_space(3))) void*)(lds), 16, 0, 0);
}

#define BARRIER()                                    \
  do {                                               \
    asm volatile("" ::: "memory");                   \
    __builtin_amdgcn_s_barrier();                    \
    asm volatile("" ::: "memory");                   \
  } while (0)
#define WAIT_LGKM0() asm volatile("s_waitcnt lgkmcnt(0)" ::: "memory")
#define WAIT_VM4() asm volatile("s_waitcnt vmcnt(4)" ::: "memory")
#define WAIT_VM0() asm volatile("s_waitcnt vmcnt(0)" ::: "memory")

// ---- fragment read macros (compile-time indices only; rule #20) ----
#define READ_A(AB, LO)                                                      \
  _Pragma("unroll") for (int mi = 0; mi < 4; ++mi) {                        \
    const int row_ = ((LO)*4 + mi) * 16 + lr;                               \
    fa[(LO)*4 + mi][0] = *(const bf16x8*)((AB) + row_ * 128 + sx0);         \
    fa[(LO)*4 + mi][1] = *(const bf16x8*)((AB) + row_ * 128 + sx1);         \
  }
#define READ_B(BB, LO)                                                      \
  _Pragma("unroll") for (int ni = 0; ni < 2; ++ni) {                        \
    const int row_ = brow0 + ((LO)*2 + ni) * 16 + lr;                       \
    fb[(LO)*2 + ni][0] = *(const bf16x8*)((BB) + row_ * 128 + sx0);         \
    fb[(LO)*2 + ni][1] = *(const bf16x8*)((BB) + row_ * 128 + sx1);         \
  }
#define MQ(M0, N0)                                                          \
  _Pragma("unroll") for (int kk = 0; kk < 2; ++kk)                          \
  _Pragma("unroll") for (int mi = 0; mi < 4; ++mi)                          \
  _Pragma("unroll") for (int ni = 0; ni < 2; ++ni)                          \
      acc[(M0) + mi][(N0) + ni] = __builtin_amdgcn_mfma_f32_16x16x32_bf16(  \
          fa[(M0) + mi][kk], fb[(N0) + ni][kk], acc[(M0) + mi][(N0) + ni],  \
          0, 0, 0);

// phase: {pre-reads || stage} -> barrier -> lgkm0 -> prio1 MFMA prio0 ->
//        {hoisted next-phase reads} -> [vm] -> barrier
#define PH2(PRE, STAGES, M0, N0, POST, WAITS) \
  do {                                        \
    PRE STAGES BARRIER();                     \
    WAIT_LGKM0();                             \
    __builtin_amdgcn_s_setprio(1);            \
    MQ(M0, N0)                                \
    __builtin_amdgcn_s_setprio(0);            \
    POST WAITS BARRIER();                     \
  } while (0)

__global__ __launch_bounds__(512, 2) void gemm256(
    const unsigned short* __restrict__ A, const unsigned short* __restrict__ B,
    float* __restrict__ C, int M, int N, int K) {
  // LDS: A halves at (buf*2+h)*16384 ; B at 65536 + (buf*2+h)*16384
  __shared__ __attribute__((aligned(1024))) char lds[131072];
  const int A00 = 0, A01 = 16384, A10 = 32768, A11 = 49152;
  const int B00 = 65536, B01 = 81920, B10 = 98304, B11 = 114688;

  const int t = threadIdx.x;
  const int l = t & 63;
  const int w = t >> 6;        // wave 0..7
  const int wm = w >> 2;       // 0..1 : 128-row half of the 256-row tile
  const int wn = w & 3;        // 0..3 : 64-col strip of the 256-col tile
  const int q = l >> 4;        // quarter-wave
  const int lr = l & 15;
  const int xc = (lr & 7) << 4;           // per-thread swizzle const
  const int sx0 = (q * 16) ^ xc;          // kk=0 slot byte (swizzled)
  const int sx1 = (64 + q * 16) ^ xc;     // kk=1 slot byte (swizzled)
  const int brow0 = (wn & 1) * 64;        // row offset inside B half
  const int srow = l >> 3;                // staging row within 8-row chunk
  const int sslot = ((l & 7) ^ ((l >> 3) & 7)) * 8;  // pre-swizzled src slot

  // T1: bijective XCD swizzle (nwg % 8 == 0 here)
  const int nwg = gridDim.x;
  int swz = blockIdx.x;
  if ((nwg & 7) == 0) swz = (swz & 7) * (nwg >> 3) + (swz >> 3);
  const int ntx = N >> 8;
  const int bx = swz % ntx;
  const int by = swz / ntx;
  const int mBase = by * 256, nBase = bx * 256;

  // read bases: wave's A half per buffer, B half per buffer
  const char* Ard0 = lds + wm * 16384;
  const char* Ard1 = lds + 32768 + wm * 16384;
  const char* Brd0 = lds + 65536 + (wn >> 1) * 16384;
  const char* Brd1 = lds + 98304 + (wn >> 1) * 16384;

  bf16x8 fa[8][2], fb[4][2];
  f32x4 acc[8][4] = {};

  auto STAGE = [&](const unsigned short* __restrict__ G, int row0, int k0,
                   int ldsOff) {
    const unsigned short* s =
        G + (size_t)(row0 + w * 8 + srow) * K + k0 + sslot;
    char* d = lds + ldsOff + w * 1024;
    gload_lds16(s, d);                          // rows 0-63 of the half
    gload_lds16(s + (size_t)64 * K, d + 8192);  // rows 64-127
  };

  // ---- prologue: tile0 (4 halves) + B10,A10 of tile1; drain tile0 ----
  STAGE(A, mBase, 0, A00);
  STAGE(A, mBase + 128, 0, A01);
  STAGE(B, nBase, 0, B00);
  STAGE(B, nBase + 128, 0, B01);
  STAGE(B, nBase, 64, B10);
  STAGE(A, mBase, 64, A10);
  WAIT_VM4();
  BARRIER();

  // ---- main loop: iteration i computes tiles 2i (buf0), 2i+1 (buf1) ----
  const int itermain = K / 128 - 1;
  for (int i = 0; i < itermain; ++i) {
    const int kA = (2 * i + 1) * 64;  // tile 2i+1
    const int kB = kA + 64;           // tile 2i+2
    const int kC = kB + 64;           // tile 2i+3
    PH2(READ_A(Ard0, 0) READ_B(Brd0, 0), STAGE(A, mBase + 128, kA, A11);,
        0, 0, READ_B(Brd0, 1), );
    PH2(, STAGE(B, nBase + 128, kA, B11);, 0, 2, READ_A(Ard0, 1), );
    PH2(, STAGE(B, nBase,       kB, B00);, 4, 0, , );
    PH2(, STAGE(A, mBase,       kB, A00);, 4, 2, , WAIT_VM4(););
    PH2(READ_A(Ard1, 0) READ_B(Brd1, 0), STAGE(A, mBase + 128, kB, A01);,
        0, 0, READ_B(Brd1, 1), );
    PH2(, STAGE(B, nBase + 128, kB, B01);, 0, 2, READ_A(Ard1, 1), );
    PH2(, STAGE(B, nBase,       kC, B10);, 4, 0, , );
    PH2(, STAGE(A, mBase,       kC, A10);, 4, 2, , WAIT_VM4(););
  }

  // ---- tail: tiles nt-2 (buf0), nt-1 (buf1) ----
  {
    const int kT = K - 64;  // last tile
    PH2(READ_A(Ard0, 0) READ_B(Brd0, 0), STAGE(A, mBase + 128, kT, A11);,
        0, 0, READ_B(Brd0, 1), );
    PH2(, STAGE(B, nBase + 128, kT, B11);, 0, 2, READ_A(Ard0, 1), );
    PH2(, , 4, 0, , );
    PH2(, , 4, 2, , WAIT_VM0(););
    PH2(READ_A(Ard1, 0) READ_B(Brd1, 0), , 0, 0, READ_B(Brd1, 1), );
    PH2(, , 0, 2, READ_A(Ard1, 1), );
    PH2(, , 4, 0, , );
    PH2(, , 4, 2, , );
  }

  // ---- epilogue: C/D layout col=lane&15, row=(lane>>4)*4+reg (m89) ----
  float* Cw = C + (size_t)(mBase + wm * 128 + q * 4) * N + nBase + wn * 64 + lr;
#pragma unroll
  for (int mi = 0; mi < 8; ++mi)
#pragma unroll
    for (int ni = 0; ni < 4; ++ni)
#pragma unroll
      for (int r = 0; r < 4; ++r)
        Cw[(size_t)(mi * 16 + r) * N + ni * 16] = acc[mi][ni][r];
}

// ---- fallback (round-1 verified fused path; used only if ws too small) ----
typedef unsigned short ushort8f __attribute__((ext_vector_type(8)));
__global__ __launch_bounds__(256) void gemm_fb(
    const float* __restrict__ Af, const float* __restrict__ Wf,
    float* __restrict__ C, int M, int N, int K) {
  __shared__ __attribute__((aligned(16))) unsigned short Ash[128 * 64];
  __shared__ __attribute__((aligned(16))) unsigned short Bsh[128 * 64];
  const int t = threadIdx.x, l = t & 63, w = t >> 6;
  const int mBase = blockIdx.y * 128, nBase = blockIdx.x * 128;
  const int wm = w >> 1, wn = w & 1;
  const int lr = l & 15, lk = (l >> 4) * 8;
  f32x4 acc[4][4] = {};
  const int frow = t >> 1, fkh = (t & 1) * 32;
  for (int k0 = 0; k0 < K; k0 += 64) {
    const float* ga = Af + (size_t)(mBase + frow) * K + k0 + fkh;
    const float* gb = Wf + (size_t)(nBase + frow) * K + k0 + fkh;
#pragma unroll
    for (int j = 0; j < 4; ++j) {
      float4 a0 = reinterpret_cast<const float4*>(ga)[2 * j];
      float4 a1 = reinterpret_cast<const float4*>(ga)[2 * j + 1];
      float4 b0 = reinterpret_cast<const float4*>(gb)[2 * j];
      float4 b1 = reinterpret_cast<const float4*>(gb)[2 * j + 1];
      ushort8f oa = {f2bf(a0.x), f2bf(a0.y), f2bf(a0.z), f2bf(a0.w),
                     f2bf(a1.x), f2bf(a1.y), f2bf(a1.z), f2bf(a1.w)};
      ushort8f ob = {f2bf(b0.x), f2bf(b0.y), f2bf(b0.z), f2bf(b0.w),
                     f2bf(b1.x), f2bf(b1.y), f2bf(b1.z), f2bf(b1.w)};
      *reinterpret_cast<ushort8f*>(&Ash[frow * 64 + fkh + j * 8]) = oa;
      *reinterpret_cast<ushort8f*>(&Bsh[frow * 64 + fkh + j * 8]) = ob;
    }
    __syncthreads();
#pragma unroll
    for (int kk = 0; kk < 2; ++kk) {
      bf16x8 a[4], b[4];
#pragma unroll
      for (int mi = 0; mi < 4; ++mi)
        a[mi] = *reinterpret_cast<const bf16x8*>(
            &Ash[(wm * 64 + mi * 16 + lr) * 64 + kk * 32 + lk]);
#pragma unroll
      for (int ni = 0; ni < 4; ++ni)
        b[ni] = *reinterpret_cast<const bf16x8*>(
            &Bsh[(wn * 64 + ni * 16 + lr) * 64 + kk * 32 + lk]);
#pragma unroll
      for (int mi = 0; mi < 4; ++mi)
#pragma unroll
        for (int ni = 0; ni < 4; ++ni)
          acc[mi][ni] = __builtin_amdgcn_mfma_f32_16x16x32_bf16(
              a[mi], b[ni], acc[mi][ni], 0, 0, 0);
    }
    __syncthreads();
  }
  const int crow0 = mBase + wm * 64 + (l >> 4) * 4;
  const int ccol0 = nBase + wn * 64 + lr;
#pragma unroll
  for (int mi = 0; mi < 4; ++mi)
#pragma unroll
    for (int ni = 0; ni < 4; ++ni)
#pragma unroll
      for (int r = 0; r < 4; ++r)
        C[(size_t)(crow0 + mi * 16 + r) * N + ccol0 + ni * 16] =
            acc[mi][ni][r];
}

extern "C" void kernel_launch(void* const* d_in, const int* in_sizes, int n_in,
                              void* d_out, int out_size, void* d_ws, size_t ws_size,
                              hipStream_t stream) {
  (void)n_in; (void)out_size;
  const float* x = (const float*)d_in[0];
  const float* wgt = (const float*)d_in[1];
  float* out = (float*)d_out;

  const long x_elems = in_sizes[0];  // M*K
  const long w_elems = in_sizes[1];  // N*K
  const int K = 4096;
  const int M = (int)(x_elems / K);  // 8192
  const int N = (int)(w_elems / K);  // 4096

  const size_t need = (size_t)(x_elems + w_elems) * sizeof(unsigned short);
  const bool ok256 =
      (M % 256 == 0) && (N % 256 == 0) && (K % 128 == 0) && (K >= 256) &&
      ws_size >= need;
  if (ok256) {
    unsigned short* Abf = (unsigned short*)d_ws;
    unsigned short* Wbf = Abf + x_elems;
    cvt_f32_to_bf16<<<2048, 256, 0, stream>>>(x, Abf, x_elems / 4);
    cvt_f32_to_bf16<<<2048, 256, 0, stream>>>(wgt, Wbf, w_elems / 4);
    gemm256<<<dim3((M / 256) * (N / 256)), 512, 0, stream>>>(Abf, Wbf, out, M,
                                                             N, K);
  } else {
    dim3 grid(N / 128, M / 128);
    gemm_fb<<<grid, 256, 0, stream>>>(x, wgt, out, M, N, K);
  }
}

// Round 5
// 266.874 us; speedup vs baseline: 1.1586x; 1.0317x over previous
//
#include <hip/hip_runtime.h>
#include <hip/hip_bf16.h>
#include <stdint.h>

// out[M,N] = x[M,K] @ weight[N,K]^T ; M=8192, N=4096, K=4096, fp32 in/out.
// Pass 1: fp32 -> bf16 convert (memory-bound) into d_ws.
// Pass 2: 256x256 8-wave 8-phase bf16 MFMA GEMM (m201 skeleton, 16x16x32,
//   0 bank conflicts verified in round 2).
// Round 5 change vs round 2: ONE barrier per phase (end-of-phase only) and
//   NO blanket lgkmcnt(0) -> compiler emits counted lgkmcnt per consumer.
//   Breaks the 2-wave/SIMD lockstep so one wave's ds_reads overlap the
//   other's MFMAs. vmcnt(4)@ph4/8 + end-of-phase barrier still cover all
//   stage->read and read->overwrite hazards (audited per-buffer).

typedef __bf16 bf16x8 __attribute__((ext_vector_type(8)));
typedef float f32x4 __attribute__((ext_vector_type(4)));

__device__ __forceinline__ unsigned short f2bf(float f) {
  unsigned u = __builtin_bit_cast(unsigned, f);
  u += 0x7FFFu + ((u >> 16) & 1u);  // RNE; Gaussian inputs, no NaN
  return (unsigned short)(u >> 16);
}

__global__ void cvt_f32_to_bf16(const float* __restrict__ src,
                                unsigned short* __restrict__ dst, long n4) {
  long i = (long)blockIdx.x * blockDim.x + threadIdx.x;
  const long stride = (long)gridDim.x * blockDim.x;
  for (; i < n4; i += stride) {
    float4 v = reinterpret_cast<const float4*>(src)[i];
    ushort4 o;
    o.x = f2bf(v.x); o.y = f2bf(v.y); o.z = f2bf(v.z); o.w = f2bf(v.w);
    reinterpret_cast<ushort4*>(dst)[i] = o;
  }
}

__device__ __forceinline__ void gload_lds16(const void* g, void* lds) {
  // async global->LDS, 16B/lane; LDS dest = wave-uniform base + lane*16
  __builtin_amdgcn_global_load_lds(
      (__attribute__((address_space(1))) void*)(g),
      (__attribute__((address_space(3))) void*)(lds), 16, 0, 0);
}

#define BARRIER()                                    \
  do {                                               \
    asm volatile("" ::: "memory");                   \
    __builtin_amdgcn_s_barrier();                    \
    asm volatile("" ::: "memory");                   \
  } while (0)
#define WAIT_VM4() asm volatile("s_waitcnt vmcnt(4)" ::: "memory")
#define WAIT_VM0() asm volatile("s_waitcnt vmcnt(0)" ::: "memory")

// ---- fragment read macros (compile-time indices only; rule #20) ----
#define READ_A(AB, LO)                                                      \
  _Pragma("unroll") for (int mi = 0; mi < 4; ++mi) {                        \
    const int row_ = ((LO)*4 + mi) * 16 + lr;                               \
    fa[(LO)*4 + mi][0] = *(const bf16x8*)((AB) + row_ * 128 + sx0);         \
    fa[(LO)*4 + mi][1] = *(const bf16x8*)((AB) + row_ * 128 + sx1);         \
  }
#define READ_B(BB, LO)                                                      \
  _Pragma("unroll") for (int ni = 0; ni < 2; ++ni) {                        \
    const int row_ = brow0 + ((LO)*2 + ni) * 16 + lr;                       \
    fb[(LO)*2 + ni][0] = *(const bf16x8*)((BB) + row_ * 128 + sx0);         \
    fb[(LO)*2 + ni][1] = *(const bf16x8*)((BB) + row_ * 128 + sx1);         \
  }
#define MQ(M0, N0)                                                          \
  _Pragma("unroll") for (int kk = 0; kk < 2; ++kk)                          \
  _Pragma("unroll") for (int mi = 0; mi < 4; ++mi)                          \
  _Pragma("unroll") for (int ni = 0; ni < 2; ++ni)                          \
      acc[(M0) + mi][(N0) + ni] = __builtin_amdgcn_mfma_f32_16x16x32_bf16(  \
          fa[(M0) + mi][kk], fb[(N0) + ni][kk], acc[(M0) + mi][(N0) + ni],  \
          0, 0, 0);

// phase: {reads || stage} -> prio1 MFMA prio0 -> [vm] -> barrier
// (no mid-phase barrier, no blanket lgkmcnt(0): compiler emits counted
//  lgkmcnt per consumer; waves drift within the phase and overlap pipes)
#define PH(READS, STAGES, M0, N0, WAITS)  \
  do {                                    \
    READS STAGES                          \
    __builtin_amdgcn_s_setprio(1);        \
    MQ(M0, N0)                            \
    __builtin_amdgcn_s_setprio(0);        \
    WAITS BARRIER();                      \
  } while (0)

__global__ __launch_bounds__(512, 2) void gemm256(
    const unsigned short* __restrict__ A, const unsigned short* __restrict__ B,
    float* __restrict__ C, int M, int N, int K) {
  // LDS: A halves at (buf*2+h)*16384 ; B at 65536 + (buf*2+h)*16384
  __shared__ __attribute__((aligned(1024))) char lds[131072];
  const int A00 = 0, A01 = 16384, A10 = 32768, A11 = 49152;
  const int B00 = 65536, B01 = 81920, B10 = 98304, B11 = 114688;

  const int t = threadIdx.x;
  const int l = t & 63;
  const int w = t >> 6;        // wave 0..7
  const int wm = w >> 2;       // 0..1 : 128-row half of the 256-row tile
  const int wn = w & 3;        // 0..3 : 64-col strip of the 256-col tile
  const int q = l >> 4;        // quarter-wave
  const int lr = l & 15;
  const int xc = (lr & 7) << 4;           // per-thread swizzle const
  const int sx0 = (q * 16) ^ xc;          // kk=0 slot byte (swizzled)
  const int sx1 = (64 + q * 16) ^ xc;     // kk=1 slot byte (swizzled)
  const int brow0 = (wn & 1) * 64;        // row offset inside B half
  const int srow = l >> 3;                // staging row within 8-row chunk
  const int sslot = ((l & 7) ^ ((l >> 3) & 7)) * 8;  // pre-swizzled src slot

  // T1: bijective XCD swizzle (nwg % 8 == 0 here)
  const int nwg = gridDim.x;
  int swz = blockIdx.x;
  if ((nwg & 7) == 0) swz = (swz & 7) * (nwg >> 3) + (swz >> 3);
  const int ntx = N >> 8;
  const int bx = swz % ntx;
  const int by = swz / ntx;
  const int mBase = by * 256, nBase = bx * 256;

  // read bases: wave's A half per buffer, B half per buffer
  const char* Ard0 = lds + wm * 16384;
  const char* Ard1 = lds + 32768 + wm * 16384;
  const char* Brd0 = lds + 65536 + (wn >> 1) * 16384;
  const char* Brd1 = lds + 98304 + (wn >> 1) * 16384;

  bf16x8 fa[8][2], fb[4][2];
  f32x4 acc[8][4] = {};

  auto STAGE = [&](const unsigned short* __restrict__ G, int row0, int k0,
                   int ldsOff) {
    const unsigned short* s =
        G + (size_t)(row0 + w * 8 + srow) * K + k0 + sslot;
    char* d = lds + ldsOff + w * 1024;
    gload_lds16(s, d);                          // rows 0-63 of the half
    gload_lds16(s + (size_t)64 * K, d + 8192);  // rows 64-127
  };

  // ---- prologue: tile0 (4 halves) + B10,A10 of tile1; drain tile0 ----
  STAGE(A, mBase, 0, A00);
  STAGE(A, mBase + 128, 0, A01);
  STAGE(B, nBase, 0, B00);
  STAGE(B, nBase + 128, 0, B01);
  STAGE(B, nBase, 64, B10);
  STAGE(A, mBase, 64, A10);
  WAIT_VM4();
  BARRIER();

  // ---- main loop: iteration i computes tiles 2i (buf0), 2i+1 (buf1) ----
  const int itermain = K / 128 - 1;
  for (int i = 0; i < itermain; ++i) {
    const int kA = (2 * i + 1) * 64;  // tile 2i+1
    const int kB = kA + 64;           // tile 2i+2
    const int kC = kB + 64;           // tile 2i+3
    PH(READ_A(Ard0, 0) READ_B(Brd0, 0), STAGE(A, mBase + 128, kA, A11);, 0, 0, );
    PH(READ_B(Brd0, 1),                 STAGE(B, nBase + 128, kA, B11);, 0, 2, );
    PH(READ_A(Ard0, 1),                 STAGE(B, nBase,       kB, B00);, 4, 0, );
    PH(,                                STAGE(A, mBase,       kB, A00);, 4, 2, WAIT_VM4(););
    PH(READ_A(Ard1, 0) READ_B(Brd1, 0), STAGE(A, mBase + 128, kB, A01);, 0, 0, );
    PH(READ_B(Brd1, 1),                 STAGE(B, nBase + 128, kB, B01);, 0, 2, );
    PH(READ_A(Ard1, 1),                 STAGE(B, nBase,       kC, B10);, 4, 0, );
    PH(,                                STAGE(A, mBase,       kC, A10);, 4, 2, WAIT_VM4(););
  }

  // ---- tail: tiles nt-2 (buf0), nt-1 (buf1) ----
  {
    const int kT = K - 64;  // last tile
    PH(READ_A(Ard0, 0) READ_B(Brd0, 0), STAGE(A, mBase + 128, kT, A11);, 0, 0, );
    PH(READ_B(Brd0, 1),                 STAGE(B, nBase + 128, kT, B11);, 0, 2, );
    PH(READ_A(Ard0, 1),                 ,                                4, 0, );
    PH(,                                ,                                4, 2, WAIT_VM0(););
    PH(READ_A(Ard1, 0) READ_B(Brd1, 0), ,                                0, 0, );
    PH(READ_B(Brd1, 1),                 ,                                0, 2, );
    PH(READ_A(Ard1, 1),                 ,                                4, 0, );
    PH(,                                ,                                4, 2, );
  }

  // ---- epilogue: C/D layout col=lane&15, row=(lane>>4)*4+reg (m89) ----
  float* Cw = C + (size_t)(mBase + wm * 128 + q * 4) * N + nBase + wn * 64 + lr;
#pragma unroll
  for (int mi = 0; mi < 8; ++mi)
#pragma unroll
    for (int ni = 0; ni < 4; ++ni)
#pragma unroll
      for (int r = 0; r < 4; ++r)
        Cw[(size_t)(mi * 16 + r) * N + ni * 16] = acc[mi][ni][r];
}

// ---- fallback (round-1 verified fused path; used only if ws too small) ----
typedef unsigned short ushort8f __attribute__((ext_vector_type(8)));
__global__ __launch_bounds__(256) void gemm_fb(
    const float* __restrict__ Af, const float* __restrict__ Wf,
    float* __restrict__ C, int M, int N, int K) {
  __shared__ __attribute__((aligned(16))) unsigned short Ash[128 * 64];
  __shared__ __attribute__((aligned(16))) unsigned short Bsh[128 * 64];
  const int t = threadIdx.x, l = t & 63, w = t >> 6;
  const int mBase = blockIdx.y * 128, nBase = blockIdx.x * 128;
  const int wm = w >> 1, wn = w & 1;
  const int lr = l & 15, lk = (l >> 4) * 8;
  f32x4 acc[4][4] = {};
  const int frow = t >> 1, fkh = (t & 1) * 32;
  for (int k0 = 0; k0 < K; k0 += 64) {
    const float* ga = Af + (size_t)(mBase + frow) * K + k0 + fkh;
    const float* gb = Wf + (size_t)(nBase + frow) * K + k0 + fkh;
#pragma unroll
    for (int j = 0; j < 4; ++j) {
      float4 a0 = reinterpret_cast<const float4*>(ga)[2 * j];
      float4 a1 = reinterpret_cast<const float4*>(ga)[2 * j + 1];
      float4 b0 = reinterpret_cast<const float4*>(gb)[2 * j];
      float4 b1 = reinterpret_cast<const float4*>(gb)[2 * j + 1];
      ushort8f oa = {f2bf(a0.x), f2bf(a0.y), f2bf(a0.z), f2bf(a0.w),
                     f2bf(a1.x), f2bf(a1.y), f2bf(a1.z), f2bf(a1.w)};
      ushort8f ob = {f2bf(b0.x), f2bf(b0.y), f2bf(b0.z), f2bf(b0.w),
                     f2bf(b1.x), f2bf(b1.y), f2bf(b1.z), f2bf(b1.w)};
      *reinterpret_cast<ushort8f*>(&Ash[frow * 64 + fkh + j * 8]) = oa;
      *reinterpret_cast<ushort8f*>(&Bsh[frow * 64 + fkh + j * 8]) = ob;
    }
    __syncthreads();
#pragma unroll
    for (int kk = 0; kk < 2; ++kk) {
      bf16x8 a[4], b[4];
#pragma unroll
      for (int mi = 0; mi < 4; ++mi)
        a[mi] = *reinterpret_cast<const bf16x8*>(
            &Ash[(wm * 64 + mi * 16 + lr) * 64 + kk * 32 + lk]);
#pragma unroll
      for (int ni = 0; ni < 4; ++ni)
        b[ni] = *reinterpret_cast<const bf16x8*>(
            &Bsh[(wn * 64 + ni * 16 + lr) * 64 + kk * 32 + lk]);
#pragma unroll
      for (int mi = 0; mi < 4; ++mi)
#pragma unroll
        for (int ni = 0; ni < 4; ++ni)
          acc[mi][ni] = __builtin_amdgcn_mfma_f32_16x16x32_bf16(
              a[mi], b[ni], acc[mi][ni], 0, 0, 0);
    }
    __syncthreads();
  }
  const int crow0 = mBase + wm * 64 + (l >> 4) * 4;
  const int ccol0 = nBase + wn * 64 + lr;
#pragma unroll
  for (int mi = 0; mi < 4; ++mi)
#pragma unroll
    for (int ni = 0; ni < 4; ++ni)
#pragma unroll
      for (int r = 0; r < 4; ++r)
        C[(size_t)(crow0 + mi * 16 + r) * N + ccol0 + ni * 16] =
            acc[mi][ni][r];
}

extern "C" void kernel_launch(void* const* d_in, const int* in_sizes, int n_in,
                              void* d_out, int out_size, void* d_ws, size_t ws_size,
                              hipStream_t stream) {
  (void)n_in; (void)out_size;
  const float* x = (const float*)d_in[0];
  const float* wgt = (const float*)d_in[1];
  float* out = (float*)d_out;

  const long x_elems = in_sizes[0];  // M*K
  const long w_elems = in_sizes[1];  // N*K
  const int K = 4096;
  const int M = (int)(x_elems / K);  // 8192
  const int N = (int)(w_elems / K);  // 4096

  const size_t need = (size_t)(x_elems + w_elems) * sizeof(unsigned short);
  const bool ok256 =
      (M % 256 == 0) && (N % 256 == 0) && (K % 128 == 0) && (K >= 256) &&
      ws_size >= need;
  if (ok256) {
    unsigned short* Abf = (unsigned short*)d_ws;
    unsigned short* Wbf = Abf + x_elems;
    cvt_f32_to_bf16<<<2048, 256, 0, stream>>>(x, Abf, x_elems / 4);
    cvt_f32_to_bf16<<<2048, 256, 0, stream>>>(wgt, Wbf, w_elems / 4);
    gemm256<<<dim3((M / 256) * (N / 256)), 512, 0, stream>>>(Abf, Wbf, out, M,
                                                             N, K);
  } else {
    dim3 grid(N / 128, M / 128);
    gemm_fb<<<grid, 256, 0, stream>>>(x, wgt, out, M, N, K);
  }
}